// Round 13
// baseline (594.862 us; speedup 1.0000x reference)
//
#include <hip/hip_runtime.h>
#include <hip/hip_bf16.h>

#define N_NODES  100000
#define N_EDGES  1600000
#define N_GRAPHS 256
#define CCH      128   // hidden channels
#define INC      64
#define N_LAYERS 5
#define SLICE_N  12500  // N_NODES/8 per XCD-slice
#define POOL_SPLIT 16
#define CAP_A    16     // first 16 neighbors: one 64B line per node
#define CAP_B    32     // overflow capacity; total CAP 48 (Poisson(16): P(deg>48) ~ 1e-11)
#define CAP      (CAP_A + CAP_B)

typedef __attribute__((ext_vector_type(8))) short  short8;
typedef __attribute__((ext_vector_type(4))) float  f32x4;

__device__ __forceinline__ float bits2f(unsigned int u){ union{unsigned int i; float f;} v; v.i=u; return v.f; }
__device__ __forceinline__ float b2f(unsigned short u){ return bits2f(((unsigned int)u)<<16); }
__device__ __forceinline__ float lo16(unsigned int u){ return bits2f(u<<16); }
__device__ __forceinline__ float hi16(unsigned int u){ return bits2f(u & 0xffff0000u); }
__device__ __forceinline__ unsigned short f2b(float f){
  union{float f; unsigned int i;} v; v.f=f;
  unsigned int r = v.i + 0x7fffu + ((v.i>>16)&1u);   // RNE
  return (unsigned short)(r>>16);
}

// ---------------- weight packing (fp32 src) into MFMA B-fragment layout (bf16) ----------------
__global__ void pack_kernel(const float* __restrict__ projw,
                            const float* __restrict__ w1,
                            const float* __restrict__ w2,
                            unsigned short* __restrict__ wp)
{
  int idx = blockIdx.x*256 + threadIdx.x;            // 172032 total
  const float* src; int rem;
  if (idx < 8192) { src = projw; rem = idx; }        // proj: K=64 -> 16 frags
  else {
    int t2 = idx - 8192;
    int mat = t2 >> 14;                              // /16384
    rem = t2 & 16383;
    src = (mat < 5) ? (w1 + mat*16384) : (w2 + (mat-5)*16384);
  }
  int f    = rem >> 9;
  int lane = (rem >> 3) & 63;
  int j    = rem & 7;
  int kk = f >> 3, nn = f & 7;
  int k = kk*32 + (lane>>4)*8 + j;
  int n = nn*16 + (lane&15);
  wp[idx] = f2b(src[k*CCH + n]);
}

// ---------------- single-pass bucketed adjacency build (XCD-sliced, split A/B storage) ----------------
__global__ __launch_bounds__(256) void fill_kernel(const int* __restrict__ src, const int* __restrict__ dst,
                                                   int* __restrict__ cnt,
                                                   int* __restrict__ esrcA, int* __restrict__ esrcB){
  int slice = blockIdx.x & 7;
  int lo = slice * SLICE_N, hi = lo + SLICE_N;
  int stride = (gridDim.x >> 3) * 256;
  for (int e = (blockIdx.x>>3)*256 + threadIdx.x; e < N_EDGES; e += stride){
    int d = __builtin_nontemporal_load(&dst[e]);
    if (d >= lo && d < hi){
      int s = __builtin_nontemporal_load(&src[e]);
      int p = atomicAdd(&cnt[d], 1);
      if (p < CAP_A)      esrcA[(size_t)d*CAP_A + p] = s;
      else if (p < CAP)   esrcB[(size_t)d*CAP_B + (p - CAP_A)] = s;
    }
  }
}

// ---------------- pool ranges via binary search on sorted batch ----------------
__global__ void bsearch_kernel(const int* __restrict__ batch, int* __restrict__ gstart){
  int g = threadIdx.x;                 // 0..255
  int lo = 0, hi = N_NODES;
  while (lo < hi){
    int mid = (lo + hi) >> 1;
    if (batch[mid] < g) lo = mid + 1; else hi = mid;
  }
  gstart[g] = lo;
  if (g == 255) gstart[256] = N_NODES;
}

// ---------------- edge aggregation: z[n] = h[n] + sum_j h[esrc[n][j]] ----------------
// one wave per node; 16 lanes x 16B cover the 256B row; 4 edge-slots in flight
__global__ __launch_bounds__(256) void aggr_kernel(const unsigned short* __restrict__ h,
                                                   const int* __restrict__ cnt,
                                                   const int* __restrict__ esrcA,
                                                   const int* __restrict__ esrcB,
                                                   unsigned short* __restrict__ z)
{
  int node = blockIdx.x*4 + (threadIdx.x>>6);        // 25000*4 = 100000 exact
  int lane = threadIdx.x & 63;
  int s = lane >> 4, c = lane & 15;                  // slot 0..3, 16B-chunk 0..15
  const uint4* h16 = (const uint4*)h;                // 16 uint4 per row
  float a[8];
  if (s == 0){
    uint4 v = h16[(size_t)node*16 + c];
    a[0]=lo16(v.x); a[1]=hi16(v.x); a[2]=lo16(v.y); a[3]=hi16(v.y);
    a[4]=lo16(v.z); a[5]=hi16(v.z); a[6]=lo16(v.w); a[7]=hi16(v.w);
  } else {
    #pragma unroll
    for (int k=0;k<8;k++) a[k] = 0.f;
  }
  int n = cnt[node]; if (n > CAP) n = CAP;
  const int* epA = esrcA + (size_t)node*CAP_A;
  const int* epB = esrcB + (size_t)node*CAP_B;
  for (int e = s; e < n; e += 4){
    int sn = (e < CAP_A) ? epA[e] : epB[e - CAP_A];
    uint4 r = h16[(size_t)sn*16 + c];
    a[0]+=lo16(r.x); a[1]+=hi16(r.x); a[2]+=lo16(r.y); a[3]+=hi16(r.y);
    a[4]+=lo16(r.z); a[5]+=hi16(r.z); a[6]+=lo16(r.w); a[7]+=hi16(r.w);
  }
  #pragma unroll
  for (int k=0;k<8;k++){
    a[k] += __shfl_xor(a[k], 16, 64);
    a[k] += __shfl_xor(a[k], 32, 64);
  }
  if (s == 0){
    uint4 o;
    o.x = (unsigned int)f2b(a[0]) | ((unsigned int)f2b(a[1])<<16);
    o.y = (unsigned int)f2b(a[2]) | ((unsigned int)f2b(a[3])<<16);
    o.z = (unsigned int)f2b(a[4]) | ((unsigned int)f2b(a[5])<<16);
    o.w = (unsigned int)f2b(a[6]) | ((unsigned int)f2b(a[7])<<16);
    ((uint4*)z)[(size_t)node*16 + c] = o;
  }
}

// ---------------- proj GEMM (reads fp32 x directly): h = x @ W + bias ----------------
__global__ __launch_bounds__(256) void projgemm_kernel(
    const float* __restrict__ X,                   // [M,64] fp32
    const unsigned short* __restrict__ Wp,
    const float* __restrict__ bias,
    unsigned short* __restrict__ out,
    int M)
{
  const int tid = threadIdx.x;
  const int wave = tid>>6, lane = tid&63;
  const int rbase = blockIdx.x*128 + wave*32;
  if (rbase >= M) return;
  const int cl = lane & 15, rg = lane >> 4;
  const bool ok1 = (rbase + 16) < M;

  f32x4 acc[2][8];
  #pragma unroll
  for (int s=0;s<2;s++)
    #pragma unroll
    for (int nn=0;nn<8;nn++) acc[s][nn] = (f32x4){0.f,0.f,0.f,0.f};

  const short8* wp8 = (const short8*)Wp;
  #pragma unroll
  for (int kk=0;kk<2;kk++){
    short8 bfr[8];
    #pragma unroll
    for (int nn=0;nn<8;nn++) bfr[nn] = wp8[(kk*8+nn)*64 + lane];
    #pragma unroll
    for (int s=0;s<2;s++){
      if (s==1 && !ok1) break;
      const float* xp = X + (size_t)(rbase + s*16 + cl)*INC + kk*32 + rg*8;
      float4 v0 = *(const float4*)xp;
      float4 v1 = *(const float4*)(xp+4);
      short8 af;
      af[0]=(short)f2b(v0.x); af[1]=(short)f2b(v0.y); af[2]=(short)f2b(v0.z); af[3]=(short)f2b(v0.w);
      af[4]=(short)f2b(v1.x); af[5]=(short)f2b(v1.y); af[6]=(short)f2b(v1.z); af[7]=(short)f2b(v1.w);
      #pragma unroll
      for (int nn=0;nn<8;nn++)
        acc[s][nn] = __builtin_amdgcn_mfma_f32_16x16x32_bf16(af, bfr[nn], acc[s][nn],0,0,0);
    }
  }

  float bc[8];
  #pragma unroll
  for (int nn=0;nn<8;nn++) bc[nn] = bias[nn*16+cl];

  #pragma unroll
  for (int s=0;s<2;s++){
    if (s==1 && !ok1) break;
    const int rowb = rbase + s*16 + rg*4;
    #pragma unroll
    for (int j=0;j<4;j++){
      unsigned short* op = out + (size_t)(rowb+j)*CCH + cl;
      #pragma unroll
      for (int nn=0;nn<8;nn++) op[nn*16] = f2b(acc[s][nn][j] + bc[nn]);
    }
  }
}

// ---------------- fused per-layer MLP: h = LN(relu(relu(z@W1+b1)@W2+b2)) ----------------
__global__ __launch_bounds__(256) void gemm12_kernel(
    const unsigned short* __restrict__ A,          // z, lda=128
    const unsigned short* __restrict__ Wp1,
    const float* __restrict__ b1,
    const unsigned short* __restrict__ Wp2,
    const float* __restrict__ b2,
    const float* __restrict__ lng,
    const float* __restrict__ lnb,
    unsigned short* __restrict__ out, int M)
{
  __shared__ unsigned short tl[4][32][136];        // per-wave turnaround tile, +8 pad
  const int tid = threadIdx.x;
  const int wave = tid>>6, lane = tid&63;
  const int rbase = blockIdx.x*128 + wave*32;
  if (rbase >= M) return;
  const int cl = lane & 15, rg = lane >> 4;
  const bool ok1 = (rbase + 16) < M;

  // ---- GEMM1: t = relu(z @ W1 + b1) -> LDS ----
  {
    f32x4 acc[2][8];
    #pragma unroll
    for (int s=0;s<2;s++)
      #pragma unroll
      for (int nn=0;nn<8;nn++) acc[s][nn] = (f32x4){0.f,0.f,0.f,0.f};

    const short8* wp8 = (const short8*)Wp1;
    #pragma unroll
    for (int kk=0;kk<4;kk++){
      short8 bfr[8];
      #pragma unroll
      for (int nn=0;nn<8;nn++) bfr[nn] = wp8[(kk*8+nn)*64 + lane];
      const unsigned short* ap = A + (size_t)(rbase+cl)*CCH + kk*32 + rg*8;
      short8 a0 = *(const short8*)ap;
      #pragma unroll
      for (int nn=0;nn<8;nn++)
        acc[0][nn] = __builtin_amdgcn_mfma_f32_16x16x32_bf16(a0, bfr[nn], acc[0][nn],0,0,0);
      if (ok1){
        short8 a1 = *(const short8*)(ap + (size_t)16*CCH);
        #pragma unroll
        for (int nn=0;nn<8;nn++)
          acc[1][nn] = __builtin_amdgcn_mfma_f32_16x16x32_bf16(a1, bfr[nn], acc[1][nn],0,0,0);
      }
    }
    float bc[8];
    #pragma unroll
    for (int nn=0;nn<8;nn++) bc[nn] = b1[nn*16+cl];
    #pragma unroll
    for (int s=0;s<2;s++){
      if (s==1 && !ok1) break;
      #pragma unroll
      for (int j=0;j<4;j++){
        int rel = s*16 + rg*4 + j;
        #pragma unroll
        for (int nn=0;nn<8;nn++){
          float t = acc[s][nn][j] + bc[nn];
          tl[wave][rel][nn*16+cl] = f2b(fmaxf(t, 0.f));
        }
      }
    }
  }
  // ---- GEMM2: out = LN(relu(t @ W2 + b2)) ----
  {
    f32x4 acc[2][8];
    #pragma unroll
    for (int s=0;s<2;s++)
      #pragma unroll
      for (int nn=0;nn<8;nn++) acc[s][nn] = (f32x4){0.f,0.f,0.f,0.f};

    const short8* wp8 = (const short8*)Wp2;
    #pragma unroll
    for (int kk=0;kk<4;kk++){
      short8 bfr[8];
      #pragma unroll
      for (int nn=0;nn<8;nn++) bfr[nn] = wp8[(kk*8+nn)*64 + lane];
      short8 a0 = *(const short8*)&tl[wave][cl][kk*32 + rg*8];
      #pragma unroll
      for (int nn=0;nn<8;nn++)
        acc[0][nn] = __builtin_amdgcn_mfma_f32_16x16x32_bf16(a0, bfr[nn], acc[0][nn],0,0,0);
      if (ok1){
        short8 a1 = *(const short8*)&tl[wave][16+cl][kk*32 + rg*8];
        #pragma unroll
        for (int nn=0;nn<8;nn++)
          acc[1][nn] = __builtin_amdgcn_mfma_f32_16x16x32_bf16(a1, bfr[nn], acc[1][nn],0,0,0);
      }
    }
    float bc[8], gg[8], bb[8];
    #pragma unroll
    for (int nn=0;nn<8;nn++){
      bc[nn] = b2[nn*16+cl];
      gg[nn] = lng[nn*16+cl];
      bb[nn] = lnb[nn*16+cl];
    }
    #pragma unroll
    for (int s=0;s<2;s++){
      if (s==1 && !ok1) break;
      float v[8][4];
      #pragma unroll
      for (int nn=0;nn<8;nn++)
        #pragma unroll
        for (int j=0;j<4;j++)
          v[nn][j] = fmaxf(acc[s][nn][j] + bc[nn], 0.f);
      #pragma unroll
      for (int j=0;j<4;j++){
        float sm=0.f, sq=0.f;
        #pragma unroll
        for (int nn=0;nn<8;nn++){ sm += v[nn][j]; sq += v[nn][j]*v[nn][j]; }
        #pragma unroll
        for (int m=1;m<16;m<<=1){ sm += __shfl_xor(sm, m, 64); sq += __shfl_xor(sq, m, 64); }
        float mean = sm * (1.f/128.f);
        float var  = fmaxf(sq * (1.f/128.f) - mean*mean, 0.f);
        float rs = rsqrtf(var + 1e-5f);
        #pragma unroll
        for (int nn=0;nn<8;nn++) v[nn][j] = (v[nn][j]-mean)*rs*gg[nn] + bb[nn];
      }
      const int rowb = rbase + s*16 + rg*4;
      #pragma unroll
      for (int j=0;j<4;j++){
        unsigned short* op = out + (size_t)(rowb+j)*CCH + cl;
        #pragma unroll
        for (int nn=0;nn<8;nn++) op[nn*16] = f2b(v[nn][j]);
      }
    }
  }
}

// ---------------- pool stage 1: per (graph, split) partial sums ----------------
__global__ __launch_bounds__(64) void pool1_kernel(const unsigned short* __restrict__ h,
                                                   const int* __restrict__ gstart,
                                                   float* __restrict__ gpart)
{
  int g = blockIdx.x >> 4;           // graph
  int sp = blockIdx.x & 15;          // split
  int lane = threadIdx.x;            // 0..63, owns 2 channels (uint)
  int n0 = gstart[g], n1 = gstart[g+1];
  const unsigned int* hu = (const unsigned int*)h;   // 64 uint per row
  float a0 = 0.f, a1 = 0.f;
  for (int n = n0 + sp; n < n1; n += POOL_SPLIT){
    unsigned int v = hu[(size_t)n*64 + lane];
    a0 += lo16(v); a1 += hi16(v);
  }
  float2* gp = (float2*)gpart;
  gp[(size_t)blockIdx.x*64 + lane] = make_float2(a0, a1);
}

// ---------------- pool stage 2: reduce splits ----------------
__global__ __launch_bounds__(64) void pool2_kernel(const float* __restrict__ gpart,
                                                   float* __restrict__ gout)
{
  int g = blockIdx.x;
  int lane = threadIdx.x;
  const float2* gp = (const float2*)gpart;
  float a0 = 0.f, a1 = 0.f;
  #pragma unroll
  for (int sp=0; sp<POOL_SPLIT; sp++){
    float2 v = gp[((size_t)g*POOL_SPLIT + sp)*64 + lane];
    a0 += v.x; a1 += v.y;
  }
  ((float2*)gout)[(size_t)g*64 + lane] = make_float2(a0, a1);
}

// ---------------- final MLP: out = relu(g@fw1+fb1)@fw2+fb2 (all fp32) ----------------
__global__ __launch_bounds__(256) void final_kernel(const float* __restrict__ gout,
                                                    const float* __restrict__ fw1,
                                                    const float* __restrict__ fb1,
                                                    const float* __restrict__ fw2,
                                                    const float* __restrict__ fb2,
                                                    float* __restrict__ out)
{
  __shared__ float gr[128];
  __shared__ float hid[256];
  int g = blockIdx.x, t = threadIdx.x;
  if (t < 128) gr[t] = gout[g*CCH + t];
  __syncthreads();
  float a = 0.f;
  for (int k=0;k<128;k++) a += gr[k] * fw1[k*256 + t];
  a += fb1[t];
  hid[t] = fmaxf(a, 0.f);
  __syncthreads();
  if (t < 128){
    float o = 0.f;
    for (int j=0;j<256;j++) o += hid[j] * fw2[j*128 + t];
    o += fb2[t];
    out[(size_t)g*CCH + t] = o;
  }
}

extern "C" void kernel_launch(void* const* d_in, const int* in_sizes, int n_in,
                              void* d_out, int out_size, void* d_ws, size_t ws_size,
                              hipStream_t stream)
{
  const float* x     = (const float*)d_in[0];
  const int*   eidx  = (const int*)d_in[1];
  const int*   batch = (const int*)d_in[2];
  const float* projw = (const float*)d_in[3];
  const float* projb = (const float*)d_in[4];
  const float* gw1   = (const float*)d_in[5];
  const float* gb1   = (const float*)d_in[6];
  const float* gw2   = (const float*)d_in[7];
  const float* gb2   = (const float*)d_in[8];
  const float* lng   = (const float*)d_in[9];
  const float* lnb   = (const float*)d_in[10];
  const float* fw1   = (const float*)d_in[11];
  const float* fb1   = (const float*)d_in[12];
  const float* fw2   = (const float*)d_in[13];
  const float* fb2   = (const float*)d_in[14];

  const int* esrc_in = eidx;
  const int* edst_in = eidx + N_EDGES;

  char* w = (char*)d_ws; size_t off = 0;
  auto wsalloc = [&](size_t b)->char*{ char* p = w + off; off += (b + 255) & ~(size_t)255; return p; };
  unsigned short* Wp   = (unsigned short*)wsalloc(172032ull*2);
  unsigned short* h    = (unsigned short*)wsalloc((size_t)N_NODES*CCH*2);
  unsigned short* z    = (unsigned short*)wsalloc((size_t)N_NODES*CCH*2);
  int*   cnt    = (int*)wsalloc((size_t)N_NODES*4);
  int*   esrcA  = (int*)wsalloc((size_t)N_NODES*CAP_A*4);
  int*   esrcB  = (int*)wsalloc((size_t)N_NODES*CAP_B*4);
  int*   gstart = (int*)wsalloc((N_GRAPHS+1)*4);
  float* gpart  = (float*)wsalloc((size_t)N_GRAPHS*POOL_SPLIT*CCH*4);
  float* gout   = (float*)wsalloc((size_t)N_GRAPHS*CCH*4);

  hipMemsetAsync(cnt, 0, (size_t)N_NODES*4, stream);

  pack_kernel<<<672, 256, 0, stream>>>(projw, gw1, gw2, Wp);
  fill_kernel<<<2000, 256, 0, stream>>>(esrc_in, edst_in, cnt, esrcA, esrcB);
  bsearch_kernel<<<1, 256, 0, stream>>>(batch, gstart);

  projgemm_kernel<<<782, 256, 0, stream>>>(x, Wp, projb, h, N_NODES);

  for (int L=0; L<N_LAYERS; ++L){
    aggr_kernel<<<25000, 256, 0, stream>>>(h, cnt, esrcA, esrcB, z);
    gemm12_kernel<<<782, 256, 0, stream>>>(z, Wp + 8192 + L*16384, gb1 + L*CCH,
                                           Wp + 8192 + (5+L)*16384, gb2 + L*CCH,
                                           lng + L*CCH, lnb + L*CCH, h, N_NODES);
  }

  pool1_kernel<<<N_GRAPHS*POOL_SPLIT, 64, 0, stream>>>(h, gstart, gpart);
  pool2_kernel<<<N_GRAPHS, 64, 0, stream>>>(gpart, gout);
  final_kernel<<<N_GRAPHS, 256, 0, stream>>>(gout, fw1, fb1, fw2, fb2, (float*)d_out);
}

// Round 15
// 575.702 us; speedup vs baseline: 1.0333x; 1.0333x over previous
//
#include <hip/hip_runtime.h>
#include <hip/hip_bf16.h>

#define N_NODES  100000
#define N_EDGES  1600000
#define N_GRAPHS 256
#define CCH      128   // hidden channels
#define INC      64
#define N_LAYERS 5
#define SLICE_N  12500  // N_NODES/8 per XCD-slice
#define POOL_SPLIT 16
#define CAP_A    16     // first 16 neighbors: one 64B line per node
#define CAP_B    32     // overflow capacity; total CAP 48 (Poisson(16): P(deg>48) ~ 1e-11)
#define CAP      (CAP_A + CAP_B)

typedef __attribute__((ext_vector_type(8))) short  short8;
typedef __attribute__((ext_vector_type(4))) float  f32x4;

__device__ __forceinline__ float bits2f(unsigned int u){ union{unsigned int i; float f;} v; v.i=u; return v.f; }
__device__ __forceinline__ float b2f(unsigned short u){ return bits2f(((unsigned int)u)<<16); }
__device__ __forceinline__ float lo16(unsigned int u){ return bits2f(u<<16); }
__device__ __forceinline__ float hi16(unsigned int u){ return bits2f(u & 0xffff0000u); }
__device__ __forceinline__ unsigned short f2b(float f){
  union{float f; unsigned int i;} v; v.f=f;
  unsigned int r = v.i + 0x7fffu + ((v.i>>16)&1u);   // RNE
  return (unsigned short)(r>>16);
}
#define ACC8(a, r) { a[0]+=lo16(r.x); a[1]+=hi16(r.x); a[2]+=lo16(r.y); a[3]+=hi16(r.y); \
                     a[4]+=lo16(r.z); a[5]+=hi16(r.z); a[6]+=lo16(r.w); a[7]+=hi16(r.w); }

// ---------------- weight packing (fp32 src) into MFMA B-fragment layout (bf16) ----------------
__global__ void pack_kernel(const float* __restrict__ projw,
                            const float* __restrict__ w1,
                            const float* __restrict__ w2,
                            unsigned short* __restrict__ wp)
{
  int idx = blockIdx.x*256 + threadIdx.x;            // 172032 total
  const float* src; int rem;
  if (idx < 8192) { src = projw; rem = idx; }        // proj: K=64 -> 16 frags
  else {
    int t2 = idx - 8192;
    int mat = t2 >> 14;                              // /16384
    rem = t2 & 16383;
    src = (mat < 5) ? (w1 + mat*16384) : (w2 + (mat-5)*16384);
  }
  int f    = rem >> 9;
  int lane = (rem >> 3) & 63;
  int j    = rem & 7;
  int kk = f >> 3, nn = f & 7;
  int k = kk*32 + (lane>>4)*8 + j;
  int n = nn*16 + (lane&15);
  wp[idx] = f2b(src[k*CCH + n]);
}

// ---------------- single-pass bucketed adjacency build (XCD-sliced, split A/B storage) ----------------
__global__ __launch_bounds__(256) void fill_kernel(const int* __restrict__ src, const int* __restrict__ dst,
                                                   int* __restrict__ cnt,
                                                   int* __restrict__ esrcA, int* __restrict__ esrcB){
  int slice = blockIdx.x & 7;
  int lo = slice * SLICE_N, hi = lo + SLICE_N;
  int stride = (gridDim.x >> 3) * 256;
  for (int e = (blockIdx.x>>3)*256 + threadIdx.x; e < N_EDGES; e += stride){
    int d = __builtin_nontemporal_load(&dst[e]);
    if (d >= lo && d < hi){
      int s = __builtin_nontemporal_load(&src[e]);
      int p = atomicAdd(&cnt[d], 1);
      if (p < CAP_A)      esrcA[(size_t)d*CAP_A + p] = s;
      else if (p < CAP)   esrcB[(size_t)d*CAP_B + (p - CAP_A)] = s;
    }
  }
}

// ---------------- pool ranges via binary search on sorted batch ----------------
__global__ void bsearch_kernel(const int* __restrict__ batch, int* __restrict__ gstart){
  int g = threadIdx.x;                 // 0..255
  int lo = 0, hi = N_NODES;
  while (lo < hi){
    int mid = (lo + hi) >> 1;
    if (batch[mid] < g) lo = mid + 1; else hi = mid;
  }
  gstart[g] = lo;
  if (g == 255) gstart[256] = N_NODES;
}

// ---------------- edge aggregation: z[n] = h[n] + sum_j h[esrc[n][j]] ----------------
// one wave per node; 16 lanes x 16B cover the 256B row; 4 edge-slots;
// 2-deep register pipeline on the gathered rows to overlap L2-miss latency
__global__ __launch_bounds__(256) void aggr_kernel(const unsigned short* __restrict__ h,
                                                   const int* __restrict__ cnt,
                                                   const int* __restrict__ esrcA,
                                                   const int* __restrict__ esrcB,
                                                   unsigned short* __restrict__ z)
{
  int node = blockIdx.x*4 + (threadIdx.x>>6);        // 25000*4 = 100000 exact
  int lane = threadIdx.x & 63;
  int s = lane >> 4, c = lane & 15;                  // slot 0..3, 16B-chunk 0..15
  const uint4* h16 = (const uint4*)h;                // 16 uint4 per row
  float a[8];
  if (s == 0){
    uint4 v = h16[(size_t)node*16 + c];
    a[0]=lo16(v.x); a[1]=hi16(v.x); a[2]=lo16(v.y); a[3]=hi16(v.y);
    a[4]=lo16(v.z); a[5]=hi16(v.z); a[6]=lo16(v.w); a[7]=hi16(v.w);
  } else {
    #pragma unroll
    for (int k=0;k<8;k++) a[k] = 0.f;
  }
  int n = cnt[node]; if (n > CAP) n = CAP;
  const int* epA = esrcA + (size_t)node*CAP_A;
  const int* epB = esrcB + (size_t)node*CAP_B;

  int e = s;
  uint4 r0, r1;
  bool p0 = e < n;
  bool p1 = (e + 4) < n;
  if (p0){
    int sn = (e < CAP_A) ? epA[e] : epB[e - CAP_A];
    r0 = h16[(size_t)sn*16 + c];
  }
  if (p1){
    int e1 = e + 4;
    int sn = (e1 < CAP_A) ? epA[e1] : epB[e1 - CAP_A];
    r1 = h16[(size_t)sn*16 + c];
  }
  while (p0){
    uint4 r2; bool p2 = (e + 8) < n;
    if (p2){
      int e2 = e + 8;
      int sn = (e2 < CAP_A) ? epA[e2] : epB[e2 - CAP_A];
      r2 = h16[(size_t)sn*16 + c];
    }
    ACC8(a, r0);
    r0 = r1; p0 = p1;
    r1 = r2; p1 = p2;
    e += 4;
  }

  #pragma unroll
  for (int k=0;k<8;k++){
    a[k] += __shfl_xor(a[k], 16, 64);
    a[k] += __shfl_xor(a[k], 32, 64);
  }
  if (s == 0){
    uint4 o;
    o.x = (unsigned int)f2b(a[0]) | ((unsigned int)f2b(a[1])<<16);
    o.y = (unsigned int)f2b(a[2]) | ((unsigned int)f2b(a[3])<<16);
    o.z = (unsigned int)f2b(a[4]) | ((unsigned int)f2b(a[5])<<16);
    o.w = (unsigned int)f2b(a[6]) | ((unsigned int)f2b(a[7])<<16);
    ((uint4*)z)[(size_t)node*16 + c] = o;
  }
}

// ---------------- proj GEMM (reads fp32 x directly): h = x @ W + bias ----------------
__global__ __launch_bounds__(256) void projgemm_kernel(
    const float* __restrict__ X,                   // [M,64] fp32
    const unsigned short* __restrict__ Wp,
    const float* __restrict__ bias,
    unsigned short* __restrict__ out,
    int M)
{
  const int tid = threadIdx.x;
  const int wave = tid>>6, lane = tid&63;
  const int rbase = blockIdx.x*128 + wave*32;
  if (rbase >= M) return;
  const int cl = lane & 15, rg = lane >> 4;
  const bool ok1 = (rbase + 16) < M;

  f32x4 acc[2][8];
  #pragma unroll
  for (int s=0;s<2;s++)
    #pragma unroll
    for (int nn=0;nn<8;nn++) acc[s][nn] = (f32x4){0.f,0.f,0.f,0.f};

  const short8* wp8 = (const short8*)Wp;
  #pragma unroll
  for (int kk=0;kk<2;kk++){
    short8 bfr[8];
    #pragma unroll
    for (int nn=0;nn<8;nn++) bfr[nn] = wp8[(kk*8+nn)*64 + lane];
    #pragma unroll
    for (int s=0;s<2;s++){
      if (s==1 && !ok1) break;
      const float* xp = X + (size_t)(rbase + s*16 + cl)*INC + kk*32 + rg*8;
      float4 v0 = *(const float4*)xp;
      float4 v1 = *(const float4*)(xp+4);
      short8 af;
      af[0]=(short)f2b(v0.x); af[1]=(short)f2b(v0.y); af[2]=(short)f2b(v0.z); af[3]=(short)f2b(v0.w);
      af[4]=(short)f2b(v1.x); af[5]=(short)f2b(v1.y); af[6]=(short)f2b(v1.z); af[7]=(short)f2b(v1.w);
      #pragma unroll
      for (int nn=0;nn<8;nn++)
        acc[s][nn] = __builtin_amdgcn_mfma_f32_16x16x32_bf16(af, bfr[nn], acc[s][nn],0,0,0);
    }
  }

  float bc[8];
  #pragma unroll
  for (int nn=0;nn<8;nn++) bc[nn] = bias[nn*16+cl];

  #pragma unroll
  for (int s=0;s<2;s++){
    if (s==1 && !ok1) break;
    const int rowb = rbase + s*16 + rg*4;
    #pragma unroll
    for (int j=0;j<4;j++){
      unsigned short* op = out + (size_t)(rowb+j)*CCH + cl;
      #pragma unroll
      for (int nn=0;nn<8;nn++) op[nn*16] = f2b(acc[s][nn][j] + bc[nn]);
    }
  }
}

// ---------------- fused per-layer MLP: h = LN(relu(relu(z@W1+b1)@W2+b2)) ----------------
__global__ __launch_bounds__(256) void gemm12_kernel(
    const unsigned short* __restrict__ A,          // z, lda=128
    const unsigned short* __restrict__ Wp1,
    const float* __restrict__ b1,
    const unsigned short* __restrict__ Wp2,
    const float* __restrict__ b2,
    const float* __restrict__ lng,
    const float* __restrict__ lnb,
    unsigned short* __restrict__ out, int M)
{
  __shared__ unsigned short tl[4][32][136];        // per-wave turnaround tile, +8 pad
  const int tid = threadIdx.x;
  const int wave = tid>>6, lane = tid&63;
  const int rbase = blockIdx.x*128 + wave*32;
  if (rbase >= M) return;
  const int cl = lane & 15, rg = lane >> 4;
  const bool ok1 = (rbase + 16) < M;

  // ---- GEMM1: t = relu(z @ W1 + b1) -> LDS ----
  {
    f32x4 acc[2][8];
    #pragma unroll
    for (int s=0;s<2;s++)
      #pragma unroll
      for (int nn=0;nn<8;nn++) acc[s][nn] = (f32x4){0.f,0.f,0.f,0.f};

    const short8* wp8 = (const short8*)Wp1;
    #pragma unroll
    for (int kk=0;kk<4;kk++){
      short8 bfr[8];
      #pragma unroll
      for (int nn=0;nn<8;nn++) bfr[nn] = wp8[(kk*8+nn)*64 + lane];
      const unsigned short* ap = A + (size_t)(rbase+cl)*CCH + kk*32 + rg*8;
      short8 a0 = *(const short8*)ap;
      #pragma unroll
      for (int nn=0;nn<8;nn++)
        acc[0][nn] = __builtin_amdgcn_mfma_f32_16x16x32_bf16(a0, bfr[nn], acc[0][nn],0,0,0);
      if (ok1){
        short8 a1 = *(const short8*)(ap + (size_t)16*CCH);
        #pragma unroll
        for (int nn=0;nn<8;nn++)
          acc[1][nn] = __builtin_amdgcn_mfma_f32_16x16x32_bf16(a1, bfr[nn], acc[1][nn],0,0,0);
      }
    }
    float bc[8];
    #pragma unroll
    for (int nn=0;nn<8;nn++) bc[nn] = b1[nn*16+cl];
    #pragma unroll
    for (int s=0;s<2;s++){
      if (s==1 && !ok1) break;
      #pragma unroll
      for (int j=0;j<4;j++){
        int rel = s*16 + rg*4 + j;
        #pragma unroll
        for (int nn=0;nn<8;nn++){
          float t = acc[s][nn][j] + bc[nn];
          tl[wave][rel][nn*16+cl] = f2b(fmaxf(t, 0.f));
        }
      }
    }
  }
  // ---- GEMM2: out = LN(relu(t @ W2 + b2)) ----
  {
    f32x4 acc[2][8];
    #pragma unroll
    for (int s=0;s<2;s++)
      #pragma unroll
      for (int nn=0;nn<8;nn++) acc[s][nn] = (f32x4){0.f,0.f,0.f,0.f};

    const short8* wp8 = (const short8*)Wp2;
    #pragma unroll
    for (int kk=0;kk<4;kk++){
      short8 bfr[8];
      #pragma unroll
      for (int nn=0;nn<8;nn++) bfr[nn] = wp8[(kk*8+nn)*64 + lane];
      short8 a0 = *(const short8*)&tl[wave][cl][kk*32 + rg*8];
      #pragma unroll
      for (int nn=0;nn<8;nn++)
        acc[0][nn] = __builtin_amdgcn_mfma_f32_16x16x32_bf16(a0, bfr[nn], acc[0][nn],0,0,0);
      if (ok1){
        short8 a1 = *(const short8*)&tl[wave][16+cl][kk*32 + rg*8];
        #pragma unroll
        for (int nn=0;nn<8;nn++)
          acc[1][nn] = __builtin_amdgcn_mfma_f32_16x16x32_bf16(a1, bfr[nn], acc[1][nn],0,0,0);
      }
    }
    float bc[8], gg[8], bb[8];
    #pragma unroll
    for (int nn=0;nn<8;nn++){
      bc[nn] = b2[nn*16+cl];
      gg[nn] = lng[nn*16+cl];
      bb[nn] = lnb[nn*16+cl];
    }
    #pragma unroll
    for (int s=0;s<2;s++){
      if (s==1 && !ok1) break;
      float v[8][4];
      #pragma unroll
      for (int nn=0;nn<8;nn++)
        #pragma unroll
        for (int j=0;j<4;j++)
          v[nn][j] = fmaxf(acc[s][nn][j] + bc[nn], 0.f);
      #pragma unroll
      for (int j=0;j<4;j++){
        float sm=0.f, sq=0.f;
        #pragma unroll
        for (int nn=0;nn<8;nn++){ sm += v[nn][j]; sq += v[nn][j]*v[nn][j]; }
        #pragma unroll
        for (int m=1;m<16;m<<=1){ sm += __shfl_xor(sm, m, 64); sq += __shfl_xor(sq, m, 64); }
        float mean = sm * (1.f/128.f);
        float var  = fmaxf(sq * (1.f/128.f) - mean*mean, 0.f);
        float rs = rsqrtf(var + 1e-5f);
        #pragma unroll
        for (int nn=0;nn<8;nn++) v[nn][j] = (v[nn][j]-mean)*rs*gg[nn] + bb[nn];
      }
      const int rowb = rbase + s*16 + rg*4;
      #pragma unroll
      for (int j=0;j<4;j++){
        unsigned short* op = out + (size_t)(rowb+j)*CCH + cl;
        #pragma unroll
        for (int nn=0;nn<8;nn++) op[nn*16] = f2b(v[nn][j]);
      }
    }
  }
}

// ---------------- pool stage 1: per (graph, split) partial sums ----------------
__global__ __launch_bounds__(64) void pool1_kernel(const unsigned short* __restrict__ h,
                                                   const int* __restrict__ gstart,
                                                   float* __restrict__ gpart)
{
  int g = blockIdx.x >> 4;           // graph
  int sp = blockIdx.x & 15;          // split
  int lane = threadIdx.x;            // 0..63, owns 2 channels (uint)
  int n0 = gstart[g], n1 = gstart[g+1];
  const unsigned int* hu = (const unsigned int*)h;   // 64 uint per row
  float a0 = 0.f, a1 = 0.f;
  for (int n = n0 + sp; n < n1; n += POOL_SPLIT){
    unsigned int v = hu[(size_t)n*64 + lane];
    a0 += lo16(v); a1 += hi16(v);
  }
  float2* gp = (float2*)gpart;
  gp[(size_t)blockIdx.x*64 + lane] = make_float2(a0, a1);
}

// ---------------- pool stage 2: reduce splits ----------------
__global__ __launch_bounds__(64) void pool2_kernel(const float* __restrict__ gpart,
                                                   float* __restrict__ gout)
{
  int g = blockIdx.x;
  int lane = threadIdx.x;
  const float2* gp = (const float2*)gpart;
  float a0 = 0.f, a1 = 0.f;
  #pragma unroll
  for (int sp=0; sp<POOL_SPLIT; sp++){
    float2 v = gp[((size_t)g*POOL_SPLIT + sp)*64 + lane];
    a0 += v.x; a1 += v.y;
  }
  ((float2*)gout)[(size_t)g*64 + lane] = make_float2(a0, a1);
}

// ---------------- final MLP: out = relu(g@fw1+fb1)@fw2+fb2 (all fp32) ----------------
__global__ __launch_bounds__(256) void final_kernel(const float* __restrict__ gout,
                                                    const float* __restrict__ fw1,
                                                    const float* __restrict__ fb1,
                                                    const float* __restrict__ fw2,
                                                    const float* __restrict__ fb2,
                                                    float* __restrict__ out)
{
  __shared__ float gr[128];
  __shared__ float hid[256];
  int g = blockIdx.x, t = threadIdx.x;
  if (t < 128) gr[t] = gout[g*CCH + t];
  __syncthreads();
  float a = 0.f;
  for (int k=0;k<128;k++) a += gr[k] * fw1[k*256 + t];
  a += fb1[t];
  hid[t] = fmaxf(a, 0.f);
  __syncthreads();
  if (t < 128){
    float o = 0.f;
    for (int j=0;j<256;j++) o += hid[j] * fw2[j*128 + t];
    o += fb2[t];
    out[(size_t)g*CCH + t] = o;
  }
}

extern "C" void kernel_launch(void* const* d_in, const int* in_sizes, int n_in,
                              void* d_out, int out_size, void* d_ws, size_t ws_size,
                              hipStream_t stream)
{
  const float* x     = (const float*)d_in[0];
  const int*   eidx  = (const int*)d_in[1];
  const int*   batch = (const int*)d_in[2];
  const float* projw = (const float*)d_in[3];
  const float* projb = (const float*)d_in[4];
  const float* gw1   = (const float*)d_in[5];
  const float* gb1   = (const float*)d_in[6];
  const float* gw2   = (const float*)d_in[7];
  const float* gb2   = (const float*)d_in[8];
  const float* lng   = (const float*)d_in[9];
  const float* lnb   = (const float*)d_in[10];
  const float* fw1   = (const float*)d_in[11];
  const float* fb1   = (const float*)d_in[12];
  const float* fw2   = (const float*)d_in[13];
  const float* fb2   = (const float*)d_in[14];

  const int* esrc_in = eidx;
  const int* edst_in = eidx + N_EDGES;

  char* w = (char*)d_ws; size_t off = 0;
  auto wsalloc = [&](size_t b)->char*{ char* p = w + off; off += (b + 255) & ~(size_t)255; return p; };
  unsigned short* Wp   = (unsigned short*)wsalloc(172032ull*2);
  unsigned short* h    = (unsigned short*)wsalloc((size_t)N_NODES*CCH*2);
  unsigned short* z    = (unsigned short*)wsalloc((size_t)N_NODES*CCH*2);
  int*   cnt    = (int*)wsalloc((size_t)N_NODES*4);
  int*   esrcA  = (int*)wsalloc((size_t)N_NODES*CAP_A*4);
  int*   esrcB  = (int*)wsalloc((size_t)N_NODES*CAP_B*4);
  int*   gstart = (int*)wsalloc((N_GRAPHS+1)*4);
  float* gpart  = (float*)wsalloc((size_t)N_GRAPHS*POOL_SPLIT*CCH*4);
  float* gout   = (float*)wsalloc((size_t)N_GRAPHS*CCH*4);

  hipMemsetAsync(cnt, 0, (size_t)N_NODES*4, stream);

  pack_kernel<<<672, 256, 0, stream>>>(projw, gw1, gw2, Wp);
  fill_kernel<<<2000, 256, 0, stream>>>(esrc_in, edst_in, cnt, esrcA, esrcB);
  bsearch_kernel<<<1, 256, 0, stream>>>(batch, gstart);

  projgemm_kernel<<<782, 256, 0, stream>>>(x, Wp, projb, h, N_NODES);

  for (int L=0; L<N_LAYERS; ++L){
    aggr_kernel<<<25000, 256, 0, stream>>>(h, cnt, esrcA, esrcB, z);
    gemm12_kernel<<<782, 256, 0, stream>>>(z, Wp + 8192 + L*16384, gb1 + L*CCH,
                                           Wp + 8192 + (5+L)*16384, gb2 + L*CCH,
                                           lng + L*CCH, lnb + L*CCH, h, N_NODES);
  }

  pool1_kernel<<<N_GRAPHS*POOL_SPLIT, 64, 0, stream>>>(h, gstart, gpart);
  pool2_kernel<<<N_GRAPHS, 64, 0, stream>>>(gpart, gout);
  final_kernel<<<N_GRAPHS, 256, 0, stream>>>(gout, fw1, fb1, fw2, fb2, (float*)d_out);
}